// Round 2
// baseline (167.910 us; speedup 1.0000x reference)
//
#include <hip/hip_runtime.h>
#include <hip/hip_fp16.h>
#include <cstdint>
#include <cstddef>

#define Bb 32
#define Ss 2048
#define Ee 1024
#define Qq 1024
#define Aa 512

typedef _Float16 half8 __attribute__((ext_vector_type(8)));
typedef float f32x4 __attribute__((ext_vector_type(4)));

// ---- workspace byte offsets ----
#define WS_PROJQ 0u        // 32*512 f32   = 65536 B
#define WS_MPART 65536u    // 32*16 f32    = 2048 B
#define WS_LPART 67584u    // 32*16 f32    = 2048 B
#define WS_CTXP  69632u    // 32*16*512 f32= 1048576 B
#define WS_WWS   1118208u  // 1024*512 f16 = 1048576 B

__device__ __forceinline__ float fast_tanh(float x) {
  float e = __expf(2.0f * x);                 // v_exp_f32 based
  return 1.0f - __fdividef(2.0f, e + 1.0f);   // exact at +-inf limits
}

// ---- W_in fp32 [E][A] -> fp16 tiled [kt][kslot][a][8]
__global__ void k_convw(const float* __restrict__ win, _Float16* __restrict__ wws) {
  int gid = blockIdx.x * 256 + threadIdx.x;   // 65536 threads: (kt, ks, a)
  int a  = gid & 511;
  int ks = (gid >> 9) & 3;
  int kt = gid >> 11;
  int k0 = kt * 32 + ks * 8;
  half8 v;
  #pragma unroll
  for (int j = 0; j < 8; ++j) v[j] = (_Float16)win[(size_t)(k0 + j) * Aa + a];
  *(half8*)(wws + ((size_t)kt * 16384 + (size_t)ks * 4096 + (size_t)a * 8)) = v;
}

// ---- proj_q[b][a] = sum_e query[b][e] * W_q[e][a]  (fp32)
__global__ void k_projq(const float* __restrict__ query, const float* __restrict__ wq,
                        float* __restrict__ projq) {
  __shared__ float red[256];
  int b  = blockIdx.y;
  int al = threadIdx.x & 63;
  int eq = threadIdx.x >> 6;
  int a  = blockIdx.x * 64 + al;
  const float* q = query + (size_t)b * Qq;
  float s = 0.f;
  int e0 = eq * 256;
  #pragma unroll 4
  for (int e = e0; e < e0 + 256; ++e)
    s += q[e] * wq[(size_t)e * Aa + a];
  red[threadIdx.x] = s;
  __syncthreads();
  if (eq == 0)
    projq[(size_t)b * Aa + a] = red[al] + red[al + 64] + red[al + 128] + red[al + 192];
}

// ---- main: per (b, s-chunk of 128): proj tile + tanh/score + local softmax + ctx partial
// A: LDS double-buffered (plain ds_write).  B: direct per-lane global loads from
// pre-tiled fp16 W (1 MB, L2-resident) — no global_load_lds, no Blds.
__global__ __launch_bounds__(512, 2)
void k_main(const float* __restrict__ inp, const _Float16* __restrict__ wws,
            const float* __restrict__ projq, const float* __restrict__ watt,
            float* __restrict__ mpart, float* __restrict__ lpart,
            float* __restrict__ ctxp)
{
  __shared__ __align__(16) _Float16 Alds[2][4 * 128 * 8];  // dbuf [ks][row][8]  16 KB
  __shared__ float pq_s[512];
  __shared__ float wa_s[512];
  __shared__ float sc4[128][4];
  __shared__ float pbuf[128];
  __shared__ float redv[8];
  __shared__ float ctx2[2][512];

  const int tid = threadIdx.x;
  const int l   = tid & 63;
  const int w   = tid >> 6;        // wave 0..7
  const int lr  = l & 15;
  const int kb  = l >> 4;          // k-block 0..3
  const int wr  = w >> 2;          // 0..1 row-wave
  const int wc  = w & 3;           // 0..3 col-wave
  const int b   = blockIdx.y;
  const int ch  = blockIdx.x;

  pq_s[tid] = projq[(size_t)b * Aa + tid];
  wa_s[tid] = watt[tid];

  // A staging: thread owns (row = w*16+lr, kslot = kb), 8 fp32 per K-step
  const int arow = w * 16 + lr;
  const float* arow_ptr = inp + ((size_t)(b * Ss + ch * 128 + arow)) * Ee + kb * 8;
  const int aoff = (kb * 128 + arow) * 8;

  f32x4 acc[4][8];
  #pragma unroll
  for (int m = 0; m < 4; ++m)
    #pragma unroll
    for (int n = 0; n < 8; ++n) acc[m][n] = (f32x4){0.f, 0.f, 0.f, 0.f};

  // B fragment base for this lane: wws half8-index kt*2048 + kb*512 + a
  const half8* Bg = (const half8*)wws + (size_t)kb * 512 + wc * 128 + lr;

  // prologue: stage A tile kt=0 into buf 0
  {
    float4 f0 = *(const float4*)(arow_ptr);
    float4 f1 = *(const float4*)(arow_ptr + 4);
    half8 h;
    h[0]=(_Float16)f0.x; h[1]=(_Float16)f0.y; h[2]=(_Float16)f0.z; h[3]=(_Float16)f0.w;
    h[4]=(_Float16)f1.x; h[5]=(_Float16)f1.y; h[6]=(_Float16)f1.z; h[7]=(_Float16)f1.w;
    *(half8*)(Alds[0] + aoff) = h;
  }
  __syncthreads();

  int p = 0;
  for (int kt = 0; kt < 32; ++kt) {
    float4 f0, f1;
    if (kt < 31) {                       // prefetch next A slice into regs
      const float* pp = arow_ptr + (size_t)(kt + 1) * 32;
      f0 = *(const float4*)(pp);
      f1 = *(const float4*)(pp + 4);
    }
    half8 bf[8];
    const half8* Bk = Bg + (size_t)kt * 2048;
    #pragma unroll
    for (int n = 0; n < 8; ++n) bf[n] = Bk[n * 16];   // 16B L2 loads, offset:n*256
    half8 af[4];
    #pragma unroll
    for (int m = 0; m < 4; ++m)
      af[m] = *(const half8*)(Alds[p] + (kb * 128 + wr * 64 + m * 16 + lr) * 8);
    #pragma unroll
    for (int m = 0; m < 4; ++m)
      #pragma unroll
      for (int n = 0; n < 8; ++n)
        acc[m][n] = __builtin_amdgcn_mfma_f32_16x16x32_f16(af[m], bf[n], acc[m][n], 0, 0, 0);
    if (kt < 31) {                       // stage kt+1 into the other buffer
      half8 h;
      h[0]=(_Float16)f0.x; h[1]=(_Float16)f0.y; h[2]=(_Float16)f0.z; h[3]=(_Float16)f0.w;
      h[4]=(_Float16)f1.x; h[5]=(_Float16)f1.y; h[6]=(_Float16)f1.z; h[7]=(_Float16)f1.w;
      *(half8*)(Alds[p ^ 1] + aoff) = h;
    }
    __syncthreads();                     // writes of kt+1 visible; reads of kt done
    p ^= 1;
  }

  // ---------------- epilogue ----------------
  // C/D layout: col = lane&15, row = (lane>>4)*4 + reg   (guide m89, dtype-independent)
  float sp[4][4];
  #pragma unroll
  for (int m = 0; m < 4; ++m)
    #pragma unroll
    for (int j = 0; j < 4; ++j) sp[m][j] = 0.f;

  #pragma unroll
  for (int n = 0; n < 8; ++n) {
    int col = wc * 128 + n * 16 + lr;
    float wan = wa_s[col], pqn = pq_s[col];
    #pragma unroll
    for (int m = 0; m < 4; ++m)
      #pragma unroll
      for (int j = 0; j < 4; ++j)
        sp[m][j] += fast_tanh(acc[m][n][j] + pqn) * wan;
  }
  #pragma unroll
  for (int m = 0; m < 4; ++m)
    #pragma unroll
    for (int j = 0; j < 4; ++j) {
      float v = sp[m][j];
      v += __shfl_xor(v, 1);
      v += __shfl_xor(v, 2);
      v += __shfl_xor(v, 4);
      v += __shfl_xor(v, 8);
      sp[m][j] = v;                      // reduced over the 16 cols held by this lane group
    }
  if (lr == 0) {
    #pragma unroll
    for (int m = 0; m < 4; ++m)
      #pragma unroll
      for (int j = 0; j < 4; ++j)
        sc4[wr * 64 + m * 16 + kb * 4 + j][wc] = sp[m][j];
  }
  __syncthreads();

  // 2) total scores per row, chunk max, exp, chunk sum
  if (tid < 128) {
    float s = sc4[tid][0] + sc4[tid][1] + sc4[tid][2] + sc4[tid][3];
    pbuf[tid] = s;
    float mx = s;
    #pragma unroll
    for (int off = 1; off < 64; off <<= 1) mx = fmaxf(mx, __shfl_xor(mx, off));
    if (l == 0) redv[w] = mx;
  }
  __syncthreads();
  float Mx = fmaxf(redv[0], redv[1]);
  if (tid < 128) {
    float pe = __expf(pbuf[tid] - Mx);
    pbuf[tid] = pe;
    float ls = pe;
    #pragma unroll
    for (int off = 1; off < 64; off <<= 1) ls += __shfl_xor(ls, off);
    if (l == 0) redv[4 + w] = ls;
  }
  __syncthreads();

  // 3) ctx partial: sum_s p[s] * proj[s][col]   (proj = pre-tanh accumulators)
  float cv[8];
  #pragma unroll
  for (int n = 0; n < 8; ++n) cv[n] = 0.f;
  #pragma unroll
  for (int m = 0; m < 4; ++m)
    #pragma unroll
    for (int j = 0; j < 4; ++j) {
      float pw = pbuf[wr * 64 + m * 16 + kb * 4 + j];
      #pragma unroll
      for (int n = 0; n < 8; ++n) cv[n] += pw * acc[m][n][j];
    }
  #pragma unroll
  for (int n = 0; n < 8; ++n) {
    float v = cv[n];
    v += __shfl_xor(v, 16);
    v += __shfl_xor(v, 32);
    cv[n] = v;                           // reduced over all 64 rows of this wave
  }
  if (l < 16) {
    #pragma unroll
    for (int n = 0; n < 8; ++n) ctx2[wr][wc * 128 + n * 16 + lr] = cv[n];
  }
  __syncthreads();

  int pi = b * 16 + ch;
  ctxp[(size_t)pi * 512 + tid] = ctx2[0][tid] + ctx2[1][tid];
  if (tid == 0) { mpart[pi] = Mx; lpart[pi] = redv[4] + redv[5]; }
}

// ---- merge chunk partials (flash-style combine)
__global__ void k_comb(const float* __restrict__ mpart, const float* __restrict__ lpart,
                       const float* __restrict__ ctxp, float* __restrict__ out) {
  int b = blockIdx.x, a = threadIdx.x;
  float Mg = -1e30f;
  #pragma unroll
  for (int i = 0; i < 16; ++i) Mg = fmaxf(Mg, mpart[b * 16 + i]);
  float den = 0.f, s = 0.f;
  #pragma unroll
  for (int i = 0; i < 16; ++i) {
    float e = __expf(mpart[b * 16 + i] - Mg);
    den += lpart[b * 16 + i] * e;
    s   += ctxp[((size_t)(b * 16 + i)) * 512 + a] * e;
  }
  out[(size_t)b * 512 + a] = s / den;
}

extern "C" void kernel_launch(void* const* d_in, const int* in_sizes, int n_in,
                              void* d_out, int out_size, void* d_ws, size_t ws_size,
                              hipStream_t stream) {
  const float* inputs = (const float*)d_in[0];
  const float* query  = (const float*)d_in[1];
  const float* W_in   = (const float*)d_in[2];
  const float* W_q    = (const float*)d_in[3];
  const float* w_att  = (const float*)d_in[4];
  float* out = (float*)d_out;

  char* ws = (char*)d_ws;
  float*    projq = (float*)(ws + WS_PROJQ);
  float*    mpart = (float*)(ws + WS_MPART);
  float*    lpart = (float*)(ws + WS_LPART);
  float*    ctxp  = (float*)(ws + WS_CTXP);
  _Float16* wws   = (_Float16*)(ws + WS_WWS);

  k_convw<<<256, 256, 0, stream>>>(W_in, wws);
  k_projq<<<dim3(8, 32), 256, 0, stream>>>(query, W_q, projq);
  k_main<<<dim3(16, 32), 512, 0, stream>>>(inputs, wws, projq, w_att, mpart, lpart, ctxp);
  k_comb<<<32, 512, 0, stream>>>(mpart, lpart, ctxp, out);
}